// Round 7
// baseline (383.661 us; speedup 1.0000x reference)
//
#include <hip/hip_runtime.h>
#include <hip/hip_bf16.h>
#include <stdint.h>

#define MM 16384
#define DD 256
#define HH 4
#define KK 16
#define DFF_ 1024

typedef __attribute__((ext_vector_type(8))) short bf16x8;
typedef __attribute__((ext_vector_type(16))) float f32x16;

__device__ __forceinline__ unsigned short f2bf(float f) {
    unsigned u = __builtin_bit_cast(unsigned, f);
    unsigned r = u + 0x7fffu + ((u >> 16) & 1u);
    return (unsigned short)(r >> 16);
}
__device__ __forceinline__ float bf2f(unsigned short h) {
    unsigned u = ((unsigned)h) << 16;
    return __builtin_bit_cast(float, u);
}
__device__ __forceinline__ float bflo(unsigned u) { return __builtin_bit_cast(float, u << 16); }
__device__ __forceinline__ float bfhi(unsigned u) { return __builtin_bit_cast(float, u & 0xffff0000u); }

// ---------------------------------------------------------------------------
// Fragment layouts (bf16, 16B chunks of 8 elems):
// A-frag (row m, k):  chunk = ((m>>5)*(KD/16) + (k>>4))*64 + ((k>>3)&1)*32 + (m&31), elem = k&7
// B-frag (col n, k):  same with n.
// v_mfma_f32_32x32x16_bf16 C/D: col=lane&31, row=(reg&3)+8*(reg>>2)+4*(lane>>5)
// kv buffer columns interleaved: group g (8 shorts) = [K4g..K4g+3, V4g..V4g+3]
// NOTE (R4): 64x128 wave tiles (acc[2][4]) spill -> 2.7% MfmaUtil. Keep 64x64.
// NOTE (R5): gelu epilogue: sigmoid-form gelu, pad-33 LDS, no barriers.
// NOTE (R6): LN fused into WO/FFN2 epilogues (wg owns full 256-col rows).
// ---------------------------------------------------------------------------

// wfrag layout (shorts): WQF@0 (blk stride 65536), KVF@131072 (131072),
//   WOF@393216 (65536), W1F@524288 (262144), W2F@1048576 (262144)
__global__ __launch_bounds__(256) void prep_weights(
        const float* __restrict__ Wq, const float* __restrict__ Wk,
        const float* __restrict__ Wv, const float* __restrict__ Wo,
        const float* __restrict__ W1, const float* __restrict__ W2,
        unsigned short* __restrict__ wf) {
    int t = blockIdx.x * blockDim.x + threadIdx.x;
    const float* src; unsigned short* dst;
    int kd, nsrc, rem, blk, e, sect;
    if (t < 131072) { sect = 0; rem = t; blk = rem >> 16; e = rem & 65535;
        src = Wq; dst = wf + blk * 65536; kd = 256; nsrc = 256; }
    else if (t < 262144) { sect = 1; rem = t - 131072; blk = rem >> 16; e = rem & 65535;
        src = Wk; dst = wf + 131072 + blk * 131072; kd = 256; nsrc = 256; }
    else if (t < 393216) { sect = 2; rem = t - 262144; blk = rem >> 16; e = rem & 65535;
        src = Wv; dst = wf + 131072 + blk * 131072; kd = 256; nsrc = 256; }
    else if (t < 524288) { sect = 0; rem = t - 393216; blk = rem >> 16; e = rem & 65535;
        src = Wo; dst = wf + 393216 + blk * 65536; kd = 256; nsrc = 256; }
    else if (t < 1048576) { sect = 0; rem = t - 524288; blk = rem >> 18; e = rem & 262143;
        src = W1; dst = wf + 524288 + blk * 262144; kd = 256; nsrc = 1024; }
    else if (t < 1572864) { sect = 0; rem = t - 1048576; blk = rem >> 18; e = rem & 262143;
        src = W2; dst = wf + 1048576 + blk * 262144; kd = 1024; nsrc = 256; }
    else return;
    int k = e / nsrc;
    int n = e - k * nsrc;
    if (sect == 1) n = (n >> 2) * 8 + (n & 3);
    else if (sect == 2) n = (n >> 2) * 8 + 4 + (n & 3);
    float v = src[(size_t)blk * kd * nsrc + e];
    int off = ((n >> 5) * (kd >> 4) + (k >> 4)) * 512 + (((k >> 3) & 1) * 32 + (n & 31)) * 8 + (k & 7);
    dst[off] = f2bf(v);
}

// LayerNorm (or plain convert) of fp32 [M,256] rows -> bf16 A-frag layout (KD=256).
__global__ __launch_bounds__(256) void ln_to_frag(
        const float* __restrict__ x, const float* __restrict__ g,
        const float* __restrict__ b, unsigned short* __restrict__ out,
        int apply_ln) {
    int wave = threadIdx.x >> 6, lane = threadIdx.x & 63;
    int m = blockIdx.x * 4 + wave;
    const float4 xv = reinterpret_cast<const float4*>(x + (size_t)m * DD)[lane];
    float vals[4] = {xv.x, xv.y, xv.z, xv.w};
    int k0 = lane * 4;
    if (apply_ln) {
        float s = vals[0] + vals[1] + vals[2] + vals[3];
        float sq = vals[0]*vals[0] + vals[1]*vals[1] + vals[2]*vals[2] + vals[3]*vals[3];
        for (int o = 32; o; o >>= 1) { s += __shfl_xor(s, o, 64); sq += __shfl_xor(sq, o, 64); }
        float mean = s * (1.0f / DD);
        float var = sq * (1.0f / DD) - mean * mean;
        float rs = rsqrtf(var + 1e-5f);
        #pragma unroll
        for (int c = 0; c < 4; ++c)
            vals[c] = (vals[c] - mean) * rs * g[k0 + c] + b[k0 + c];
    }
    int chunk = ((m >> 5) * (DD >> 4) + (k0 >> 4)) * 64 + ((k0 >> 3) & 1) * 32 + (m & 31);
    ushort4 o4 = make_ushort4(f2bf(vals[0]), f2bf(vals[1]), f2bf(vals[2]), f2bf(vals[3]));
    *reinterpret_cast<ushort4*>(out + (size_t)chunk * 8 + (k0 & 7)) = o4;
}

template <int KGH>
__device__ __forceinline__ void compute_tile(
        const bf16x8* __restrict__ a0, const bf16x8* __restrict__ a1,
        const bf16x8* __restrict__ b0, const bf16x8* __restrict__ b1,
        f32x16 acc[2][2]) {
    #pragma unroll 4
    for (int g = 0; g < KGH; ++g) {
        bf16x8 av0 = a0[g * 64];
        bf16x8 av1 = a1[g * 64];
        bf16x8 bv0 = b0[g * 64];
        bf16x8 bv1 = b1[g * 64];
        acc[0][0] = __builtin_amdgcn_mfma_f32_32x32x16_bf16(av0, bv0, acc[0][0], 0, 0, 0);
        acc[0][1] = __builtin_amdgcn_mfma_f32_32x32x16_bf16(av0, bv1, acc[0][1], 0, 0, 0);
        acc[1][0] = __builtin_amdgcn_mfma_f32_32x32x16_bf16(av1, bv0, acc[1][0], 0, 0, 0);
        acc[1][1] = __builtin_amdgcn_mfma_f32_32x32x16_bf16(av1, bv1, acc[1][1], 0, 0, 0);
    }
}

// GEMM + residual (+bias) + optional fused LayerNorm.
// wg = 64 rows x 256 cols, 8 waves = {4 n-tiles} x {2 k-halves}, split-K LDS reduce.
// Outputs: out_f32[m,n] = v (pre-LN, with resid);  out_frag = LN(v) in bf16 A-frag.
template <int KD, bool BIAS, bool DO_LN>
__global__ __launch_bounds__(512) void gemm_ln(
        const bf16x8* __restrict__ A, const bf16x8* __restrict__ B,
        const float* __restrict__ resid, const float* __restrict__ bias,
        const float* __restrict__ lng, const float* __restrict__ lnb,
        float* __restrict__ out_f32, unsigned short* __restrict__ out_frag) {
    constexpr int KG = KD / 16, KGH = KG / 2;
    __shared__ float lds[4 * 64 * 64 + 512 + 128];
    float* lnsum = lds + 16384;   // [4][64]
    float* lnsq  = lnsum + 256;   // [4][64]
    float* lnstat = lnsq + 256;   // [64][2] mean, rs
    int wave = threadIdx.x >> 6, lane = threadIdx.x & 63;
    int wn = wave & 3, kh = wave >> 2;
    int m0 = blockIdx.x * 64;
    int n0 = wn * 64;
    const bf16x8* a0 = A + ((size_t)(m0 >> 5) * KG + kh * KGH) * 64 + lane;
    const bf16x8* a1 = a0 + (size_t)KG * 64;
    const bf16x8* b0 = B + ((size_t)(n0 >> 5) * KG + kh * KGH) * 64 + lane;
    const bf16x8* b1 = b0 + (size_t)KG * 64;
    f32x16 acc[2][2] = {};
    compute_tile<KGH>(a0, a1, b0, b1, acc);
    int col = lane & 31, rq = (lane >> 5) * 4;
    float* skbuf = &lds[wn * 4096];
    if (kh == 1) {
        #pragma unroll
        for (int i = 0; i < 2; ++i)
        #pragma unroll
        for (int j = 0; j < 2; ++j)
        #pragma unroll
        for (int r = 0; r < 16; ++r) {
            int rl = (r & 3) + 8 * (r >> 2) + rq;
            skbuf[(i * 32 + rl) * 64 + j * 32 + col] = acc[i][j][r];
        }
    }
    __syncthreads();
    if (kh == 0) {
        #pragma unroll
        for (int i = 0; i < 2; ++i)
        #pragma unroll
        for (int j = 0; j < 2; ++j)
        #pragma unroll
        for (int r = 0; r < 16; ++r) {
            int rl = (r & 3) + 8 * (r >> 2) + rq;
            int m = m0 + i * 32 + rl;
            int n = n0 + j * 32 + col;
            float v = acc[i][j][r] + skbuf[(i * 32 + rl) * 64 + j * 32 + col];
            if (BIAS) v += bias[n];
            v += resid[(size_t)m * 256 + n];
            out_f32[(size_t)m * 256 + n] = v;
            acc[i][j][r] = v;
        }
    }
    if constexpr (DO_LN) {
        if (kh == 0) {
            #pragma unroll
            for (int i = 0; i < 2; ++i)
            #pragma unroll
            for (int r = 0; r < 16; ++r) {
                float v0 = acc[i][0][r], v1 = acc[i][1][r];
                float p = v0 + v1, q = v0 * v0 + v1 * v1;
                #pragma unroll
                for (int o = 1; o < 32; o <<= 1) {
                    p += __shfl_xor(p, o, 64);
                    q += __shfl_xor(q, o, 64);
                }
                if (col == 0) {
                    int row64 = i * 32 + (r & 3) + 8 * (r >> 2) + rq;
                    lnsum[wn * 64 + row64] = p;
                    lnsq[wn * 64 + row64] = q;
                }
            }
        }
        __syncthreads();
        if (wave == 0) {
            int row = lane;
            float s = lnsum[row] + lnsum[64 + row] + lnsum[128 + row] + lnsum[192 + row];
            float q = lnsq[row] + lnsq[64 + row] + lnsq[128 + row] + lnsq[192 + row];
            float mean = s * (1.0f / 256.0f);
            float var = q * (1.0f / 256.0f) - mean * mean;
            lnstat[row * 2] = mean;
            lnstat[row * 2 + 1] = rsqrtf(var + 1e-5f);
        }
        __syncthreads();
        if (kh == 1) return;
        // LN + frag store via wave-private pad-33 transpose (reuse skbuf region).
        for (int i = 0; i < 2; ++i)
        for (int j = 0; j < 2; ++j) {
            #pragma unroll
            for (int r = 0; r < 16; ++r) {
                int rl = (r & 3) + 8 * (r >> 2) + rq;
                int row64 = i * 32 + rl;
                float mean = lnstat[row64 * 2], rs = lnstat[row64 * 2 + 1];
                int n = n0 + j * 32 + col;
                float vln = (acc[i][j][r] - mean) * rs * lng[n] + lnb[n];
                skbuf[rl * 33 + col] = vln;
            }
            #pragma unroll
            for (int it = 0; it < 2; ++it) {
                int task = lane + it * 64;
                int row = task >> 2, cc = task & 3;
                int m = m0 + i * 32 + row;
                int k = n0 + j * 32 + cc * 8;
                float* p = &skbuf[row * 33 + cc * 8];
                unsigned short us[8];
                #pragma unroll
                for (int e = 0; e < 8; ++e) us[e] = f2bf(p[e]);
                int chunk = ((m >> 5) * 16 + (k >> 4)) * 64 + ((k >> 3) & 1) * 32 + (m & 31);
                reinterpret_cast<uint4*>(out_frag)[chunk] = *reinterpret_cast<uint4*>(us);
            }
        }
    }
}

// FFN1 with GELU epilogue -> bf16 A-frag (out KD=1024). 2 waves, 128x64 wg tile.
__global__ __launch_bounds__(128) void gemm_gelu(
        const bf16x8* __restrict__ A, const bf16x8* __restrict__ B,
        unsigned short* __restrict__ outp, const float* __restrict__ bias) {
    constexpr int KG = 16;
    __shared__ float lds[2 * 32 * 33];
    int wave = threadIdx.x >> 6, lane = threadIdx.x & 63;
    int m0 = blockIdx.x * 128 + wave * 64;
    int n0 = blockIdx.y * 64;
    const bf16x8* a0 = A + ((size_t)(m0 >> 5) * KG) * 64 + lane;
    const bf16x8* a1 = a0 + (size_t)KG * 64;
    const bf16x8* b0 = B + ((size_t)(n0 >> 5) * KG) * 64 + lane;
    const bf16x8* b1 = b0 + (size_t)KG * 64;
    f32x16 acc[2][2] = {};
    compute_tile<KG>(a0, a1, b0, b1, acc);
    int col = lane & 31, rq = (lane >> 5) * 4;
    float* wlds = &lds[wave * 1056];
    for (int i = 0; i < 2; ++i)
    for (int j = 0; j < 2; ++j) {
        #pragma unroll
        for (int r = 0; r < 16; ++r) {
            int row = (r & 3) + 8 * (r >> 2) + rq;
            int n = n0 + j * 32 + col;
            float v = acc[i][j][r] + bias[n];
            float arg = v * (1.5957691216f + 0.0713548163f * v * v);
            v = v * __frcp_rn(1.0f + __expf(-arg));
            wlds[row * 33 + col] = v;
        }
        #pragma unroll
        for (int it = 0; it < 2; ++it) {
            int task = lane + it * 64;
            int row = task >> 2, cc = task & 3;
            int m = m0 + i * 32 + row;
            int k = n0 + j * 32 + cc * 8;
            float* p = &wlds[row * 33 + cc * 8];
            unsigned short us[8];
            #pragma unroll
            for (int e = 0; e < 8; ++e) us[e] = f2bf(p[e]);
            int chunk = ((m >> 5) * 64 + (k >> 4)) * 64 + ((k >> 3) & 1) * 32 + (m & 31);
            reinterpret_cast<uint4*>(outp)[chunk] = *reinterpret_cast<uint4*>(us);
        }
    }
}

// Fused Q and KV projections. grid.y 0..3 -> Q cols, 4..11 -> KV cols. Split-K x2.
__global__ __launch_bounds__(256) void gemm_qkv(
        const bf16x8* __restrict__ Aq, const bf16x8* __restrict__ Akv,
        const bf16x8* __restrict__ Bq, const bf16x8* __restrict__ Bkv,
        unsigned short* __restrict__ qout, unsigned short* __restrict__ kvout) {
    constexpr int KG = 16, KGH = 8;
    __shared__ float lds[2 * 64 * 64];
    int wave = threadIdx.x >> 6, lane = threadIdx.x & 63;
    int mhalf = wave & 1, khalf = wave >> 1;
    int y = blockIdx.y;
    bool isQ = y < 4;
    const bf16x8* A = isQ ? Aq : Akv;
    const bf16x8* B = isQ ? Bq : Bkv;
    unsigned short* out = isQ ? qout : kvout;
    int nstride = isQ ? 256 : 512;
    int n0 = (isQ ? y : y - 4) * 64;
    int m0 = blockIdx.x * 128 + mhalf * 64;
    const bf16x8* a0 = A + ((size_t)(m0 >> 5) * KG + khalf * KGH) * 64 + lane;
    const bf16x8* a1 = a0 + (size_t)KG * 64;
    const bf16x8* b0 = B + ((size_t)(n0 >> 5) * KG + khalf * KGH) * 64 + lane;
    const bf16x8* b1 = b0 + (size_t)KG * 64;
    f32x16 acc[2][2] = {};
    compute_tile<KGH>(a0, a1, b0, b1, acc);
    int col = lane & 31, rq = (lane >> 5) * 4;
    if (khalf == 1) {
        #pragma unroll
        for (int i = 0; i < 2; ++i)
        #pragma unroll
        for (int j = 0; j < 2; ++j)
        #pragma unroll
        for (int r = 0; r < 16; ++r) {
            int row = (r & 3) + 8 * (r >> 2) + rq + i * 32;
            lds[mhalf * 4096 + row * 64 + j * 32 + col] = acc[i][j][r];
        }
    }
    __syncthreads();
    if (khalf == 1) return;
    #pragma unroll
    for (int i = 0; i < 2; ++i)
    #pragma unroll
    for (int j = 0; j < 2; ++j)
    #pragma unroll
    for (int r = 0; r < 16; ++r) {
        int row = (r & 3) + 8 * (r >> 2) + rq;
        float v = acc[i][j][r] + lds[mhalf * 4096 + (row + i * 32) * 64 + j * 32 + col];
        out[(size_t)(m0 + i * 32 + row) * nstride + n0 + j * 32 + col] = f2bf(v);
    }
}

// One wave per point. lane = h*16+s; dims d0 = h*64+s*4.
// Distributed scores; pe handled algebraically (see R4 notes).
__global__ __launch_bounds__(256) void attn_kernel(
        const unsigned short* __restrict__ q, const unsigned short* __restrict__ kv,
        const float* __restrict__ coord, const float* __restrict__ ctx_coord,
        const int* __restrict__ knn,
        const float* __restrict__ pe_w, const float* __restrict__ pe_b,
        unsigned short* __restrict__ out_frag) {
    int wave = threadIdx.x >> 6, lane = threadIdx.x & 63;
    int m = blockIdx.x * 4 + wave;
    int s = lane & 15;
    int d0 = (lane >> 4) * 64 + s * 4;

    ushort4 qv4 = *reinterpret_cast<const ushort4*>(q + (size_t)m * DD + d0);
    float qx = bf2f(qv4.x), qy = bf2f(qv4.y), qz = bf2f(qv4.z), qw = bf2f(qv4.w);
    float4 pw0 = *reinterpret_cast<const float4*>(pe_w + d0);
    float4 pw1 = *reinterpret_cast<const float4*>(pe_w + DD + d0);
    float4 pw2 = *reinterpret_cast<const float4*>(pe_w + 2 * DD + d0);
    float4 pbv = *reinterpret_cast<const float4*>(pe_b + d0);

    float cx = coord[m * 3], cy = coord[m * 3 + 1], cz = coord[m * 3 + 2];
    int myidx = knn[(size_t)m * KK + s];
    int icm = myidx < 0 ? 0 : myidx;
    float rx = cx - ctx_coord[icm * 3];
    float ry = cy - ctx_coord[icm * 3 + 1];
    float rz = cz - ctx_coord[icm * 3 + 2];

    float t0 = qx * pw0.x + qy * pw0.y + qz * pw0.z + qw * pw0.w;
    float t1 = qx * pw1.x + qy * pw1.y + qz * pw1.z + qw * pw1.w;
    float t2 = qx * pw2.x + qy * pw2.y + qz * pw2.z + qw * pw2.w;
    float t3 = qx * pbv.x + qy * pbv.y + qz * pbv.z + qw * pbv.w;
    #pragma unroll
    for (int o = 1; o < 16; o <<= 1) {
        t0 += __shfl_xor(t0, o, 64);
        t1 += __shfl_xor(t1, o, 64);
        t2 += __shfl_xor(t2, o, 64);
        t3 += __shfl_xor(t3, o, 64);
    }

    float sc_own = 0.0f;
    unsigned vlo[KK], vhi[KK];
    #pragma unroll
    for (int j = 0; j < KK; ++j) {
        int ij = __shfl(myidx, j, 64);
        int ic = ij < 0 ? 0 : ij;
        uint4 kvv = *reinterpret_cast<const uint4*>(kv + (size_t)ic * 512 + (size_t)(d0 >> 2) * 8);
        vlo[j] = kvv.z; vhi[j] = kvv.w;
        float p = qx * bflo(kvv.x) + qy * bfhi(kvv.x)
                + qz * bflo(kvv.y) + qw * bfhi(kvv.y);
        p += __shfl_xor(p, 1, 64);
        p += __shfl_xor(p, 2, 64);
        p += __shfl_xor(p, 4, 64);
        p += __shfl_xor(p, 8, 64);
        sc_own = (j == s) ? p : sc_own;
    }
    float corr = rx * t0 + ry * t1 + rz * t2 + t3;
    sc_own = (myidx >= 0) ? (sc_own + corr) * 0.125f : -1e9f;

    float mx = sc_own;
    mx = fmaxf(mx, __shfl_xor(mx, 1, 64));
    mx = fmaxf(mx, __shfl_xor(mx, 2, 64));
    mx = fmaxf(mx, __shfl_xor(mx, 4, 64));
    mx = fmaxf(mx, __shfl_xor(mx, 8, 64));
    float e = __expf(sc_own - mx);
    float sum = e;
    sum += __shfl_xor(sum, 1, 64);
    sum += __shfl_xor(sum, 2, 64);
    sum += __shfl_xor(sum, 4, 64);
    sum += __shfl_xor(sum, 8, 64);
    float w_own = e * __frcp_rn(sum);

    float wrx = w_own * rx, wry = w_own * ry, wrz = w_own * rz;
    #pragma unroll
    for (int o = 1; o < 16; o <<= 1) {
        wrx += __shfl_xor(wrx, o, 64);
        wry += __shfl_xor(wry, o, 64);
        wrz += __shfl_xor(wrz, o, 64);
    }

    int gbase = lane & 48;
    float ax = 0.f, ay = 0.f, az = 0.f, aw = 0.f;
    #pragma unroll
    for (int j = 0; j < KK; ++j) {
        float wj = __shfl(w_own, gbase + j, 64);
        ax += wj * bflo(vlo[j]);
        ay += wj * bfhi(vlo[j]);
        az += wj * bflo(vhi[j]);
        aw += wj * bfhi(vhi[j]);
    }
    ax += wrx * pw0.x + wry * pw1.x + wrz * pw2.x + pbv.x;
    ay += wrx * pw0.y + wry * pw1.y + wrz * pw2.y + pbv.y;
    az += wrx * pw0.z + wry * pw1.z + wrz * pw2.z + pbv.z;
    aw += wrx * pw0.w + wry * pw1.w + wrz * pw2.w + pbv.w;

    ushort4 o4 = make_ushort4(f2bf(ax), f2bf(ay), f2bf(az), f2bf(aw));
    int chunk = ((m >> 5) * (DD >> 4) + (d0 >> 4)) * 64 + ((d0 >> 3) & 1) * 32 + (m & 31);
    *reinterpret_cast<ushort4*>(out_frag + (size_t)chunk * 8 + (d0 & 7)) = o4;
}

extern "C" void kernel_launch(void* const* d_in, const int* in_sizes, int n_in,
                              void* d_out, int out_size, void* d_ws, size_t ws_size,
                              hipStream_t stream) {
    const float* feat_a = (const float*)d_in[0];
    const float* coord_a = (const float*)d_in[1];
    const float* feat_b = (const float*)d_in[2];
    const float* coord_b = (const float*)d_in[3];
    const float* Wq = (const float*)d_in[4];
    const float* Wk = (const float*)d_in[5];
    const float* Wv = (const float*)d_in[6];
    const float* Wo = (const float*)d_in[7];
    const float* ln1_g = (const float*)d_in[8];
    const float* ln1_b = (const float*)d_in[9];
    const float* pe_w = (const float*)d_in[10];
    const float* pe_b = (const float*)d_in[11];
    const float* W1 = (const float*)d_in[12];
    const float* b1 = (const float*)d_in[13];
    const float* W2 = (const float*)d_in[14];
    const float* b2 = (const float*)d_in[15];
    const float* ln2_g = (const float*)d_in[16];
    const float* ln2_b = (const float*)d_in[17];
    const int* knn_a2a = (const int*)d_in[18];
    const int* knn_a2b = (const int*)d_in[19];

    char* ws = (char*)d_ws;
    unsigned short* wfrag = (unsigned short*)ws;                  // 3 MB (4 MB region)
    float* xmid = (float*)(ws + (4ull << 20));                    // 16 MB
    float* xout0 = (float*)(ws + (20ull << 20));                  // 16 MB
    unsigned short* qbuf = (unsigned short*)(ws + (36ull << 20)); // 8 MB
    unsigned short* kvbuf = (unsigned short*)(ws + (52ull << 20));// 16 MB
    unsigned short* xnf = (unsigned short*)(ws + (68ull << 20));  // 8 MB
    unsigned short* ctxf = (unsigned short*)(ws + (76ull << 20)); // 8 MB
    unsigned short* attnf = (unsigned short*)(ws + (84ull << 20));// 8 MB -> 92 MB
    unsigned short* geluf = (unsigned short*)(ws + (36ull << 20));// 32 MB, overlays q/kv (dead by FFN)

    const unsigned short* WQF = wfrag;
    const unsigned short* KVF = wfrag + 131072;
    const unsigned short* WOF = wfrag + 393216;
    const unsigned short* W1F = wfrag + 524288;
    const unsigned short* W2F = wfrag + 1048576;

    prep_weights<<<(1572864 + 255) / 256, 256, 0, stream>>>(Wq, Wk, Wv, Wo, W1, W2, wfrag);

    // Block 0 inputs
    ln_to_frag<<<MM / 4, 256, 0, stream>>>(feat_a, nullptr, nullptr, ctxf, 0);
    ln_to_frag<<<MM / 4, 256, 0, stream>>>(feat_a, ln1_g, ln1_b, xnf, 1);

    // ---- Block 0 ----
    gemm_qkv<<<dim3(MM / 128, 12), 256, 0, stream>>>(
        (const bf16x8*)xnf, (const bf16x8*)ctxf,
        (const bf16x8*)WQF, (const bf16x8*)KVF, qbuf, kvbuf);
    attn_kernel<<<MM / 4, 256, 0, stream>>>(qbuf, kvbuf, coord_a, coord_a, knn_a2a,
                                            pe_w, pe_b, attnf);
    // xmid = x + attn@Wo ; xnf = LN2(xmid)
    gemm_ln<256, false, true><<<MM / 64, 512, 0, stream>>>(
        (const bf16x8*)attnf, (const bf16x8*)WOF, feat_a, nullptr,
        ln2_g, ln2_b, xmid, xnf);
    gemm_gelu<<<dim3(MM / 128, 16), 128, 0, stream>>>(
        (const bf16x8*)xnf, (const bf16x8*)W1F, geluf, b1);
    // xout0 = xmid + gelu@W2 + b2 ; xnf = LN1[blk1](xout0)
    gemm_ln<1024, true, true><<<MM / 64, 512, 0, stream>>>(
        (const bf16x8*)geluf, (const bf16x8*)(W2F), xmid, b2,
        ln1_g + DD, ln1_b + DD, xout0, xnf);

    // Block 1 context
    ln_to_frag<<<MM / 4, 256, 0, stream>>>(feat_b, nullptr, nullptr, ctxf, 0);

    // ---- Block 1 ----
    gemm_qkv<<<dim3(MM / 128, 12), 256, 0, stream>>>(
        (const bf16x8*)xnf, (const bf16x8*)ctxf,
        (const bf16x8*)(WQF + 65536), (const bf16x8*)(KVF + 131072), qbuf, kvbuf);
    attn_kernel<<<MM / 4, 256, 0, stream>>>(qbuf, kvbuf, coord_a, coord_b, knn_a2b,
                                            pe_w + 3 * DD, pe_b + DD, attnf);
    gemm_ln<256, false, true><<<MM / 64, 512, 0, stream>>>(
        (const bf16x8*)attnf, (const bf16x8*)(WOF + 65536), xout0, nullptr,
        ln2_g + DD, ln2_b + DD, xmid, xnf);
    gemm_gelu<<<dim3(MM / 128, 16), 128, 0, stream>>>(
        (const bf16x8*)xnf, (const bf16x8*)(W1F + 262144), geluf, b1 + DFF_);
    gemm_ln<1024, true, false><<<MM / 64, 512, 0, stream>>>(
        (const bf16x8*)geluf, (const bf16x8*)(W2F + 262144), xmid, b2 + DD,
        nullptr, nullptr, (float*)d_out, nullptr);
}

// Round 8
// 362.003 us; speedup vs baseline: 1.0598x; 1.0598x over previous
//
#include <hip/hip_runtime.h>
#include <hip/hip_bf16.h>
#include <stdint.h>

#define MM 16384
#define DD 256
#define HH 4
#define KK 16
#define DFF_ 1024

typedef __attribute__((ext_vector_type(8))) short bf16x8;
typedef __attribute__((ext_vector_type(16))) float f32x16;
typedef __attribute__((ext_vector_type(2))) float f32x2;

__device__ __forceinline__ unsigned short f2bf(float f) {
    unsigned u = __builtin_bit_cast(unsigned, f);
    unsigned r = u + 0x7fffu + ((u >> 16) & 1u);
    return (unsigned short)(r >> 16);
}
__device__ __forceinline__ float bf2f(unsigned short h) {
    unsigned u = ((unsigned)h) << 16;
    return __builtin_bit_cast(float, u);
}

// ---------------------------------------------------------------------------
// Fragment layouts (bf16, 16B chunks of 8 elems):
// A-frag (row m, k):  chunk = ((m>>5)*(KD/16) + (k>>4))*64 + ((k>>3)&1)*32 + (m&31), elem = k&7
// B-frag (col n, k):  same with n.
// v_mfma_f32_32x32x16_bf16 C/D: col=lane&31, row=(reg&3)+8*(reg>>2)+4*(lane>>5)
// kv buffer: fp8 e4m3 rows of 512 B, interleaved groups of 8 bytes:
//   group g = [K4g..K4g+3 | V4g..V4g+3]  (matches prep interleave of WK/WV cols)
// NOTE (R4): 64x128 wave tiles (acc[2][4]) spill -> 2.7% MfmaUtil. Keep 64x64.
// NOTE (R5): gelu epilogue: sigmoid-form gelu, pad-33 LDS, no barriers.
// NOTE (R6): gemm_ln fusion (1 wg/CU, 68KB LDS, half-idle waves) regressed; reverted.
// NOTE (R7): attn gather is XCD-L2-replication bound (8 x kv bytes); fp8 KV halves it.
// ---------------------------------------------------------------------------

// wfrag layout (shorts): WQF@0 (blk stride 65536), KVF@131072 (131072),
//   WOF@393216 (65536), W1F@524288 (262144), W2F@1048576 (262144)
__global__ __launch_bounds__(256) void prep_weights(
        const float* __restrict__ Wq, const float* __restrict__ Wk,
        const float* __restrict__ Wv, const float* __restrict__ Wo,
        const float* __restrict__ W1, const float* __restrict__ W2,
        unsigned short* __restrict__ wf) {
    int t = blockIdx.x * blockDim.x + threadIdx.x;
    const float* src; unsigned short* dst;
    int kd, nsrc, rem, blk, e, sect;
    if (t < 131072) { sect = 0; rem = t; blk = rem >> 16; e = rem & 65535;
        src = Wq; dst = wf + blk * 65536; kd = 256; nsrc = 256; }
    else if (t < 262144) { sect = 1; rem = t - 131072; blk = rem >> 16; e = rem & 65535;
        src = Wk; dst = wf + 131072 + blk * 131072; kd = 256; nsrc = 256; }
    else if (t < 393216) { sect = 2; rem = t - 262144; blk = rem >> 16; e = rem & 65535;
        src = Wv; dst = wf + 131072 + blk * 131072; kd = 256; nsrc = 256; }
    else if (t < 524288) { sect = 0; rem = t - 393216; blk = rem >> 16; e = rem & 65535;
        src = Wo; dst = wf + 393216 + blk * 65536; kd = 256; nsrc = 256; }
    else if (t < 1048576) { sect = 0; rem = t - 524288; blk = rem >> 18; e = rem & 262143;
        src = W1; dst = wf + 524288 + blk * 262144; kd = 256; nsrc = 1024; }
    else if (t < 1572864) { sect = 0; rem = t - 1048576; blk = rem >> 18; e = rem & 262143;
        src = W2; dst = wf + 1048576 + blk * 262144; kd = 1024; nsrc = 256; }
    else return;
    int k = e / nsrc;
    int n = e - k * nsrc;
    if (sect == 1) n = (n >> 2) * 8 + (n & 3);
    else if (sect == 2) n = (n >> 2) * 8 + 4 + (n & 3);
    float v = src[(size_t)blk * kd * nsrc + e];
    int off = ((n >> 5) * (kd >> 4) + (k >> 4)) * 512 + (((k >> 3) & 1) * 32 + (n & 31)) * 8 + (k & 7);
    dst[off] = f2bf(v);
}

// LayerNorm (or plain convert) of fp32 [M,256] rows -> bf16 A-frag layout (KD=256).
__global__ __launch_bounds__(256) void ln_to_frag(
        const float* __restrict__ x, const float* __restrict__ g,
        const float* __restrict__ b, unsigned short* __restrict__ out,
        int apply_ln) {
    int wave = threadIdx.x >> 6, lane = threadIdx.x & 63;
    int m = blockIdx.x * 4 + wave;
    const float4 xv = reinterpret_cast<const float4*>(x + (size_t)m * DD)[lane];
    float vals[4] = {xv.x, xv.y, xv.z, xv.w};
    int k0 = lane * 4;
    if (apply_ln) {
        float s = vals[0] + vals[1] + vals[2] + vals[3];
        float sq = vals[0]*vals[0] + vals[1]*vals[1] + vals[2]*vals[2] + vals[3]*vals[3];
        for (int o = 32; o; o >>= 1) { s += __shfl_xor(s, o, 64); sq += __shfl_xor(sq, o, 64); }
        float mean = s * (1.0f / DD);
        float var = sq * (1.0f / DD) - mean * mean;
        float rs = rsqrtf(var + 1e-5f);
        #pragma unroll
        for (int c = 0; c < 4; ++c)
            vals[c] = (vals[c] - mean) * rs * g[k0 + c] + b[k0 + c];
    }
    int chunk = ((m >> 5) * (DD >> 4) + (k0 >> 4)) * 64 + ((k0 >> 3) & 1) * 32 + (m & 31);
    ushort4 o4 = make_ushort4(f2bf(vals[0]), f2bf(vals[1]), f2bf(vals[2]), f2bf(vals[3]));
    *reinterpret_cast<ushort4*>(out + (size_t)chunk * 8 + (k0 & 7)) = o4;
}

constexpr int GOUT_F32 = 0;
constexpr int GOUT_BF16 = 1;
constexpr int GOUT_GELU_FRAG = 2;

template <int KGH>
__device__ __forceinline__ void compute_tile(
        const bf16x8* __restrict__ a0, const bf16x8* __restrict__ a1,
        const bf16x8* __restrict__ b0, const bf16x8* __restrict__ b1,
        f32x16 acc[2][2]) {
    #pragma unroll 4
    for (int g = 0; g < KGH; ++g) {
        bf16x8 av0 = a0[g * 64];
        bf16x8 av1 = a1[g * 64];
        bf16x8 bv0 = b0[g * 64];
        bf16x8 bv1 = b1[g * 64];
        acc[0][0] = __builtin_amdgcn_mfma_f32_32x32x16_bf16(av0, bv0, acc[0][0], 0, 0, 0);
        acc[0][1] = __builtin_amdgcn_mfma_f32_32x32x16_bf16(av0, bv1, acc[0][1], 0, 0, 0);
        acc[1][0] = __builtin_amdgcn_mfma_f32_32x32x16_bf16(av1, bv0, acc[1][0], 0, 0, 0);
        acc[1][1] = __builtin_amdgcn_mfma_f32_32x32x16_bf16(av1, bv1, acc[1][1], 0, 0, 0);
    }
}

// C = A(frag) x B(frag). Workgroup = 128 rows x 64 cols.
// SPLITK=1: 2 waves (m-halves). SPLITK=2: 4 waves (m-half x k-half), LDS reduce.
template <int KD, int NOUT, int SPLITK, int MODE, bool RESID, bool BIAS>
__global__ __launch_bounds__(SPLITK * 128) void gemm_frag(
        const bf16x8* __restrict__ A, const bf16x8* __restrict__ B,
        void* __restrict__ outp, const float* __restrict__ resid,
        const float* __restrict__ bias, int out_kd) {
    static_assert(MODE != GOUT_GELU_FRAG || SPLITK == 1, "gelu path is 2-wave only");
    constexpr int KG = KD / 16;
    constexpr int KGH = KG / SPLITK;
    __shared__ float lds[SPLITK == 2 ? 2 * 64 * 64 : 2 * 32 * 33];
    int wave = threadIdx.x >> 6, lane = threadIdx.x & 63;
    int mhalf = wave & 1;
    int khalf = (SPLITK == 2) ? (wave >> 1) : 0;
    int m0 = blockIdx.x * 128 + mhalf * 64;
    int n0 = blockIdx.y * 64;
    const bf16x8* a0 = A + ((size_t)(m0 >> 5) * KG + khalf * KGH) * 64 + lane;
    const bf16x8* a1 = a0 + (size_t)KG * 64;
    const bf16x8* b0 = B + ((size_t)(n0 >> 5) * KG + khalf * KGH) * 64 + lane;
    const bf16x8* b1 = b0 + (size_t)KG * 64;
    f32x16 acc[2][2] = {};
    compute_tile<KGH>(a0, a1, b0, b1, acc);
    int col = lane & 31, rq = (lane >> 5) * 4;
    if constexpr (SPLITK == 2) {
        if (khalf == 1) {
            #pragma unroll
            for (int i = 0; i < 2; ++i)
            #pragma unroll
            for (int j = 0; j < 2; ++j)
            #pragma unroll
            for (int r = 0; r < 16; ++r) {
                int row = (r & 3) + 8 * (r >> 2) + rq + i * 32;
                lds[mhalf * 4096 + row * 64 + j * 32 + col] = acc[i][j][r];
            }
        }
        __syncthreads();
        if (khalf == 1) return;
        #pragma unroll
        for (int i = 0; i < 2; ++i)
        #pragma unroll
        for (int j = 0; j < 2; ++j)
        #pragma unroll
        for (int r = 0; r < 16; ++r) {
            int row = (r & 3) + 8 * (r >> 2) + rq + i * 32;
            acc[i][j][r] += lds[mhalf * 4096 + row * 64 + j * 32 + col];
        }
    }
    if constexpr (MODE != GOUT_GELU_FRAG) {
        #pragma unroll
        for (int i = 0; i < 2; ++i)
        #pragma unroll
        for (int j = 0; j < 2; ++j) {
            #pragma unroll
            for (int r = 0; r < 16; ++r) {
                int row = (r & 3) + 8 * (r >> 2) + rq;
                int m = m0 + i * 32 + row;
                int n = n0 + j * 32 + col;
                float v = acc[i][j][r];
                if (BIAS) v += bias[n];
                if (RESID) v += resid[(size_t)m * NOUT + n];
                if (MODE == GOUT_F32) ((float*)outp)[(size_t)m * NOUT + n] = v;
                else ((unsigned short*)outp)[(size_t)m * NOUT + n] = f2bf(v);
            }
        }
    } else {
        // Wave-private pad-33 tile; no barriers (in-wave LDS ordering suffices).
        float* wlds = &lds[wave * 1056];
        for (int i = 0; i < 2; ++i)
        for (int j = 0; j < 2; ++j) {
            #pragma unroll
            for (int r = 0; r < 16; ++r) {
                int row = (r & 3) + 8 * (r >> 2) + rq;
                int n = n0 + j * 32 + col;
                float v = acc[i][j][r] + bias[n];
                float arg = v * (1.5957691216f + 0.0713548163f * v * v);
                v = v * __frcp_rn(1.0f + __expf(-arg));
                wlds[row * 33 + col] = v;
            }
            #pragma unroll
            for (int it = 0; it < 2; ++it) {
                int task = lane + it * 64;
                int row = task >> 2, cc = task & 3;
                int m = m0 + i * 32 + row;
                int k = n0 + j * 32 + cc * 8;
                float* p = &wlds[row * 33 + cc * 8];
                unsigned short us[8];
                #pragma unroll
                for (int e = 0; e < 8; ++e) us[e] = f2bf(p[e]);
                int chunk = ((m >> 5) * (out_kd >> 4) + (k >> 4)) * 64 + ((k >> 3) & 1) * 32 + (m & 31);
                reinterpret_cast<uint4*>(outp)[chunk] = *reinterpret_cast<uint4*>(us);
            }
        }
    }
}

// Fused Q and KV projections. grid.y 0..3 -> Q cols (bf16 out), 4..11 -> KV cols
// (fp8 e4m3 out, 512 B rows). Split-K x2.
__global__ __launch_bounds__(256) void gemm_qkv(
        const bf16x8* __restrict__ Aq, const bf16x8* __restrict__ Akv,
        const bf16x8* __restrict__ Bq, const bf16x8* __restrict__ Bkv,
        unsigned short* __restrict__ qout, unsigned char* __restrict__ kvout) {
    constexpr int KG = 16, KGH = 8;
    __shared__ float lds[2 * 64 * 64];
    int wave = threadIdx.x >> 6, lane = threadIdx.x & 63;
    int mhalf = wave & 1, khalf = wave >> 1;
    int y = blockIdx.y;
    bool isQ = y < 4;
    const bf16x8* A = isQ ? Aq : Akv;
    const bf16x8* B = isQ ? Bq : Bkv;
    int n0 = (isQ ? y : y - 4) * 64;
    int m0 = blockIdx.x * 128 + mhalf * 64;
    const bf16x8* a0 = A + ((size_t)(m0 >> 5) * KG + khalf * KGH) * 64 + lane;
    const bf16x8* a1 = a0 + (size_t)KG * 64;
    const bf16x8* b0 = B + ((size_t)(n0 >> 5) * KG + khalf * KGH) * 64 + lane;
    const bf16x8* b1 = b0 + (size_t)KG * 64;
    f32x16 acc[2][2] = {};
    compute_tile<KGH>(a0, a1, b0, b1, acc);
    int col = lane & 31, rq = (lane >> 5) * 4;
    if (khalf == 1) {
        #pragma unroll
        for (int i = 0; i < 2; ++i)
        #pragma unroll
        for (int j = 0; j < 2; ++j)
        #pragma unroll
        for (int r = 0; r < 16; ++r) {
            int row = (r & 3) + 8 * (r >> 2) + rq + i * 32;
            lds[mhalf * 4096 + row * 64 + j * 32 + col] = acc[i][j][r];
        }
    }
    __syncthreads();
    if (khalf == 1) return;
    #pragma unroll
    for (int i = 0; i < 2; ++i)
    #pragma unroll
    for (int j = 0; j < 2; ++j)
    #pragma unroll
    for (int r = 0; r < 16; ++r) {
        int row = (r & 3) + 8 * (r >> 2) + rq;
        int m = m0 + i * 32 + row;
        int n = n0 + j * 32 + col;
        float v = acc[i][j][r] + lds[mhalf * 4096 + (row + i * 32) * 64 + j * 32 + col];
        if (isQ) qout[(size_t)m * 256 + n] = f2bf(v);
        else kvout[(size_t)m * 512 + n] =
            (unsigned char)(__builtin_amdgcn_cvt_pk_fp8_f32(v, v, 0, false) & 0xff);
    }
}

// One wave per point. lane = h*16+s; dims d0 = h*64+s*4.
// Distributed scores; pe handled algebraically. kv rows: 512 B fp8, groups of
// 8 bytes = [K4 | V4]; lane loads uint2 (K word + V word).
__global__ __launch_bounds__(256) void attn_kernel(
        const unsigned short* __restrict__ q, const unsigned char* __restrict__ kv,
        const float* __restrict__ coord, const float* __restrict__ ctx_coord,
        const int* __restrict__ knn,
        const float* __restrict__ pe_w, const float* __restrict__ pe_b,
        unsigned short* __restrict__ out_frag) {
    int wave = threadIdx.x >> 6, lane = threadIdx.x & 63;
    int m = blockIdx.x * 4 + wave;
    int s = lane & 15;
    int d0 = (lane >> 4) * 64 + s * 4;

    ushort4 qv4 = *reinterpret_cast<const ushort4*>(q + (size_t)m * DD + d0);
    float qx = bf2f(qv4.x), qy = bf2f(qv4.y), qz = bf2f(qv4.z), qw = bf2f(qv4.w);
    float4 pw0 = *reinterpret_cast<const float4*>(pe_w + d0);
    float4 pw1 = *reinterpret_cast<const float4*>(pe_w + DD + d0);
    float4 pw2 = *reinterpret_cast<const float4*>(pe_w + 2 * DD + d0);
    float4 pbv = *reinterpret_cast<const float4*>(pe_b + d0);

    float cx = coord[m * 3], cy = coord[m * 3 + 1], cz = coord[m * 3 + 2];
    int myidx = knn[(size_t)m * KK + s];
    int icm = myidx < 0 ? 0 : myidx;
    float rx = cx - ctx_coord[icm * 3];
    float ry = cy - ctx_coord[icm * 3 + 1];
    float rz = cz - ctx_coord[icm * 3 + 2];

    float t0 = qx * pw0.x + qy * pw0.y + qz * pw0.z + qw * pw0.w;
    float t1 = qx * pw1.x + qy * pw1.y + qz * pw1.z + qw * pw1.w;
    float t2 = qx * pw2.x + qy * pw2.y + qz * pw2.z + qw * pw2.w;
    float t3 = qx * pbv.x + qy * pbv.y + qz * pbv.z + qw * pbv.w;
    #pragma unroll
    for (int o = 1; o < 16; o <<= 1) {
        t0 += __shfl_xor(t0, o, 64);
        t1 += __shfl_xor(t1, o, 64);
        t2 += __shfl_xor(t2, o, 64);
        t3 += __shfl_xor(t3, o, 64);
    }

    float sc_own = 0.0f;
    unsigned vpk[KK];
    #pragma unroll
    for (int j = 0; j < KK; ++j) {
        int ij = __shfl(myidx, j, 64);
        int ic = ij < 0 ? 0 : ij;
        uint2 kvv = *reinterpret_cast<const uint2*>(kv + (size_t)ic * 512 + (d0 >> 2) * 8);
        vpk[j] = kvv.y;
        f32x2 k01 = __builtin_amdgcn_cvt_pk_f32_fp8(kvv.x, false);
        f32x2 k23 = __builtin_amdgcn_cvt_pk_f32_fp8(kvv.x, true);
        float p = qx * k01.x + qy * k01.y + qz * k23.x + qw * k23.y;
        p += __shfl_xor(p, 1, 64);
        p += __shfl_xor(p, 2, 64);
        p += __shfl_xor(p, 4, 64);
        p += __shfl_xor(p, 8, 64);
        sc_own = (j == s) ? p : sc_own;
    }
    float corr = rx * t0 + ry * t1 + rz * t2 + t3;
    sc_own = (myidx >= 0) ? (sc_own + corr) * 0.125f : -1e9f;

    float mx = sc_own;
    mx = fmaxf(mx, __shfl_xor(mx, 1, 64));
    mx = fmaxf(mx, __shfl_xor(mx, 2, 64));
    mx = fmaxf(mx, __shfl_xor(mx, 4, 64));
    mx = fmaxf(mx, __shfl_xor(mx, 8, 64));
    float e = __expf(sc_own - mx);
    float sum = e;
    sum += __shfl_xor(sum, 1, 64);
    sum += __shfl_xor(sum, 2, 64);
    sum += __shfl_xor(sum, 4, 64);
    sum += __shfl_xor(sum, 8, 64);
    float w_own = e * __frcp_rn(sum);

    float wrx = w_own * rx, wry = w_own * ry, wrz = w_own * rz;
    #pragma unroll
    for (int o = 1; o < 16; o <<= 1) {
        wrx += __shfl_xor(wrx, o, 64);
        wry += __shfl_xor(wry, o, 64);
        wrz += __shfl_xor(wrz, o, 64);
    }

    int gbase = lane & 48;
    float ax = 0.f, ay = 0.f, az = 0.f, aw = 0.f;
    #pragma unroll
    for (int j = 0; j < KK; ++j) {
        float wj = __shfl(w_own, gbase + j, 64);
        f32x2 v01 = __builtin_amdgcn_cvt_pk_f32_fp8(vpk[j], false);
        f32x2 v23 = __builtin_amdgcn_cvt_pk_f32_fp8(vpk[j], true);
        ax += wj * v01.x;
        ay += wj * v01.y;
        az += wj * v23.x;
        aw += wj * v23.y;
    }
    ax += wrx * pw0.x + wry * pw1.x + wrz * pw2.x + pbv.x;
    ay += wrx * pw0.y + wry * pw1.y + wrz * pw2.y + pbv.y;
    az += wrx * pw0.z + wry * pw1.z + wrz * pw2.z + pbv.z;
    aw += wrx * pw0.w + wry * pw1.w + wrz * pw2.w + pbv.w;

    ushort4 o4 = make_ushort4(f2bf(ax), f2bf(ay), f2bf(az), f2bf(aw));
    int chunk = ((m >> 5) * (DD >> 4) + (d0 >> 4)) * 64 + ((d0 >> 3) & 1) * 32 + (m & 31);
    *reinterpret_cast<ushort4*>(out_frag + (size_t)chunk * 8 + (d0 & 7)) = o4;
}

extern "C" void kernel_launch(void* const* d_in, const int* in_sizes, int n_in,
                              void* d_out, int out_size, void* d_ws, size_t ws_size,
                              hipStream_t stream) {
    const float* feat_a = (const float*)d_in[0];
    const float* coord_a = (const float*)d_in[1];
    const float* feat_b = (const float*)d_in[2];
    const float* coord_b = (const float*)d_in[3];
    const float* Wq = (const float*)d_in[4];
    const float* Wk = (const float*)d_in[5];
    const float* Wv = (const float*)d_in[6];
    const float* Wo = (const float*)d_in[7];
    const float* ln1_g = (const float*)d_in[8];
    const float* ln1_b = (const float*)d_in[9];
    const float* pe_w = (const float*)d_in[10];
    const float* pe_b = (const float*)d_in[11];
    const float* W1 = (const float*)d_in[12];
    const float* b1 = (const float*)d_in[13];
    const float* W2 = (const float*)d_in[14];
    const float* b2 = (const float*)d_in[15];
    const float* ln2_g = (const float*)d_in[16];
    const float* ln2_b = (const float*)d_in[17];
    const int* knn_a2a = (const int*)d_in[18];
    const int* knn_a2b = (const int*)d_in[19];

    char* ws = (char*)d_ws;
    unsigned short* wfrag = (unsigned short*)ws;                  // 3 MB (4 MB region)
    float* xmid = (float*)(ws + (4ull << 20));                    // 16 MB
    float* xout0 = (float*)(ws + (20ull << 20));                  // 16 MB
    unsigned short* qbuf = (unsigned short*)(ws + (36ull << 20)); // 8 MB
    unsigned char* kvbuf = (unsigned char*)(ws + (52ull << 20));  // 8 MB (fp8)
    unsigned short* xnf = (unsigned short*)(ws + (68ull << 20));  // 8 MB
    unsigned short* ctxf = (unsigned short*)(ws + (76ull << 20)); // 8 MB
    unsigned short* attnf = (unsigned short*)(ws + (84ull << 20));// 8 MB -> 92 MB
    unsigned short* geluf = (unsigned short*)(ws + (36ull << 20));// 32 MB, overlays q/kv (dead by FFN)

    const unsigned short* WQF = wfrag;
    const unsigned short* KVF = wfrag + 131072;
    const unsigned short* WOF = wfrag + 393216;
    const unsigned short* W1F = wfrag + 524288;
    const unsigned short* W2F = wfrag + 1048576;

    prep_weights<<<(1572864 + 255) / 256, 256, 0, stream>>>(Wq, Wk, Wv, Wo, W1, W2, wfrag);

    for (int blk = 0; blk < 2; ++blk) {
        const float* x_in = blk ? xout0 : feat_a;
        const float* ctx = blk ? feat_b : feat_a;
        const float* ccrd = blk ? coord_b : coord_a;
        const int* knn = blk ? knn_a2b : knn_a2a;
        float* x_out_final = blk ? (float*)d_out : xout0;

        ln_to_frag<<<MM / 4, 256, 0, stream>>>(ctx, nullptr, nullptr, ctxf, 0);
        ln_to_frag<<<MM / 4, 256, 0, stream>>>(x_in, ln1_g + blk * DD, ln1_b + blk * DD, xnf, 1);

        gemm_qkv<<<dim3(MM / 128, 12), 256, 0, stream>>>(
            (const bf16x8*)xnf, (const bf16x8*)ctxf,
            (const bf16x8*)(WQF + blk * 65536), (const bf16x8*)(KVF + blk * 131072),
            qbuf, kvbuf);

        attn_kernel<<<MM / 4, 256, 0, stream>>>(qbuf, kvbuf, coord_a, ccrd, knn,
                                                pe_w + blk * 3 * DD, pe_b + blk * DD, attnf);

        gemm_frag<256, 256, 2, GOUT_F32, true, false><<<dim3(MM / 128, 4), 256, 0, stream>>>(
            (const bf16x8*)attnf, (const bf16x8*)(WOF + blk * 65536), xmid, x_in, nullptr, 0);

        ln_to_frag<<<MM / 4, 256, 0, stream>>>(xmid, ln2_g + blk * DD, ln2_b + blk * DD, xnf, 1);

        gemm_frag<256, 1024, 1, GOUT_GELU_FRAG, false, true><<<dim3(MM / 128, 16), 128, 0, stream>>>(
            (const bf16x8*)xnf, (const bf16x8*)(W1F + blk * 262144), geluf, nullptr,
            b1 + blk * DFF_, 1024);

        gemm_frag<1024, 256, 2, GOUT_F32, true, true><<<dim3(MM / 128, 4), 256, 0, stream>>>(
            (const bf16x8*)geluf, (const bf16x8*)(W2F + blk * 262144), x_out_final, xmid,
            b2 + blk * DD, 0);
    }
}